// Round 4
// baseline (475.292 us; speedup 1.0000x reference)
//
#include <hip/hip_runtime.h>
#include <hip/hip_bf16.h>

// Problem constants
#define B_   4
#define T_   2048
#define C_   1024
#define H_   16
#define HD_  64
#define BH_  (B_*H_)    // 64
#define M_   (B_*T_)    // 8192
#define N1_  (3*C_)     // 3072

typedef __hip_bfloat16 bf16;
typedef __attribute__((ext_vector_type(8))) __bf16 bf16x8v;   // MFMA A/B frag (4 VGPRs)
typedef __attribute__((ext_vector_type(4))) float  f32x4;     // MFMA C/D frag

__device__ __forceinline__ f32x4 mfma16(bf16x8v a, bf16x8v b, f32x4 c) {
    return __builtin_amdgcn_mfma_f32_16x16x32_bf16(a, b, c, 0, 0, 0);
}

// async global->LDS DMA, 16 B per lane (lds dest = wave-uniform base + lane*16)
typedef __attribute__((address_space(3))) unsigned int       lds_u32;
typedef const __attribute__((address_space(1))) unsigned int glb_u32;
__device__ __forceinline__ void async16(void* lds, const void* g) {
    __builtin_amdgcn_global_load_lds((glb_u32*)g, (lds_u32*)lds, 16, 0, 0);
}

// DPP 16-lane-row reductions (VALU pipe, replaces ds_swizzle shuffles)
template<int CTRL>
__device__ __forceinline__ float dpp_rot(float x) {
    int v = __builtin_amdgcn_update_dpp(0, __float_as_int(x), CTRL, 0xF, 0xF, true);
    return __int_as_float(v);
}
__device__ __forceinline__ float row16_max(float x) {
    x = fmaxf(x, dpp_rot<0x121>(x));   // ror:1
    x = fmaxf(x, dpp_rot<0x122>(x));   // ror:2
    x = fmaxf(x, dpp_rot<0x124>(x));   // ror:4
    x = fmaxf(x, dpp_rot<0x128>(x));   // ror:8
    return x;
}
__device__ __forceinline__ float row16_sum(float x) {
    x += dpp_rot<0x121>(x);
    x += dpp_rot<0x122>(x);
    x += dpp_rot<0x124>(x);
    x += dpp_rot<0x128>(x);
    return x;
}

// ---------------------------------------------------------------------------
// fp32 -> bf16 elementwise convert (x), 8 elems/thread
// ---------------------------------------------------------------------------
__global__ void convert_f32_bf16(const float* __restrict__ in, bf16* __restrict__ out) {
    const int i = blockIdx.x * blockDim.x + threadIdx.x;   // per-8-elements
    float f[8];
    *(float4*)(f)     = ((const float4*)in)[i*2];
    *(float4*)(f + 4) = ((const float4*)in)[i*2 + 1];
    bf16 t[8];
#pragma unroll
    for (int j = 0; j < 8; ++j) t[j] = __float2bfloat16(f[j]);
    ((uint4*)out)[i] = *(uint4*)t;
}

// ---------------------------------------------------------------------------
// Tiled transpose + fp32->bf16 convert: out[n][k] = bf16(in[k][n]).
// ---------------------------------------------------------------------------
__global__ void transpose_f32_to_bf16(const float* __restrict__ in,
                                      bf16* __restrict__ out, int K, int N) {
    __shared__ float t[32][33];
    const int n0 = blockIdx.x * 32, k0 = blockIdx.y * 32;
    const int c  = threadIdx.x & 31;
    const int rr = threadIdx.x >> 5;
#pragma unroll
    for (int i = 0; i < 4; ++i)
        t[c][rr + 8*i] = in[(size_t)(k0 + rr + 8*i) * N + n0 + c];
    __syncthreads();
#pragma unroll
    for (int i = 0; i < 4; ++i)
        out[(size_t)(n0 + rr + 8*i) * K + k0 + c] = __float2bfloat16(t[rr + 8*i][c]);
}

// ---------------------------------------------------------------------------
// GEMM (m97 structure): C[M,N] = A[M,K](bf16) @ B, B given transposed bf16 Bt[N][K].
// 128x128 tile, 256 threads = 4 waves 2x2, 4x4 MFMA frags/wave, BK=32.
// Staging via global_load_lds width=16 into UNPADDED [128][32] LDS (DMA layout
// must be lane-contiguous: lane i -> row base+(i>>2), col (i&3)*8).
// EPI=0: fp32 store. EPI=1: qkv scatter (q scaled 0.125; v transposed).
// ---------------------------------------------------------------------------
template<int EPI>
__global__ __launch_bounds__(256, 2)
void gemm_lds(const bf16* __restrict__ A, const bf16* __restrict__ Bt,
              float* __restrict__ Cmat, int N, int K,
              bf16* __restrict__ qb, bf16* __restrict__ kb, bf16* __restrict__ vb)
{
    __shared__ bf16 Alds[128][32];   // 8 KB, unpadded (DMA constraint)
    __shared__ bf16 Blds[128][32];   // 8 KB

    const int tid  = threadIdx.x;
    const int wave = tid >> 6, lane = tid & 63;
    const int quad = lane >> 4, l16 = lane & 15;
    const int wm   = (wave >> 1) * 64, wn = (wave & 1) * 64;
    const size_t row0 = (size_t)blockIdx.y * 128;
    const size_t col0 = (size_t)blockIdx.x * 128;

    const f32x4 z4 = {0.f, 0.f, 0.f, 0.f};
    f32x4 acc[4][4];
#pragma unroll
    for (int mi = 0; mi < 4; ++mi)
#pragma unroll
        for (int ni = 0; ni < 4; ++ni) acc[mi][ni] = z4;

    // DMA staging: wave w covers rows [w*32, w*32+32) of each tile, 2 instrs
    const int sr = lane >> 2;           // 0..15
    const int sc = (lane & 3) * 8;      // 0,8,16,24
    const bf16* gA0 = A  + (row0 + wave*32 + sr) * (size_t)K + sc;
    const bf16* gA1 = gA0 + (size_t)16 * K;
    const bf16* gB0 = Bt + (col0 + wave*32 + sr) * (size_t)K + sc;
    const bf16* gB1 = gB0 + (size_t)16 * K;
    bf16* lA0 = &Alds[wave*32][0];
    bf16* lA1 = &Alds[wave*32 + 16][0];
    bf16* lB0 = &Blds[wave*32][0];
    bf16* lB1 = &Blds[wave*32 + 16][0];

    for (int k0 = 0; k0 < K; k0 += 32) {
        async16(lA0, gA0 + k0);
        async16(lA1, gA1 + k0);
        async16(lB0, gB0 + k0);
        async16(lB1, gB1 + k0);
        __syncthreads();   // drains vmcnt (DMA complete) + barrier

        bf16x8v af[4], bfr[4];
#pragma unroll
        for (int i = 0; i < 4; ++i) {
            af[i]  = *(const bf16x8v*)(&Alds[wm + i*16 + l16][quad*8]);
            bfr[i] = *(const bf16x8v*)(&Blds[wn + i*16 + l16][quad*8]);
        }
#pragma unroll
        for (int mi = 0; mi < 4; ++mi)
#pragma unroll
            for (int ni = 0; ni < 4; ++ni)
                acc[mi][ni] = mfma16(af[mi], bfr[ni], acc[mi][ni]);
        __syncthreads();   // protect LDS before next DMA
    }

#pragma unroll
    for (int mi = 0; mi < 4; ++mi) {
        const size_t rowb = row0 + wm + mi*16 + quad*4;
#pragma unroll
        for (int ni = 0; ni < 4; ++ni) {
            const size_t col = col0 + wn + ni*16 + l16;
#pragma unroll
            for (int r = 0; r < 4; ++r) {
                const float v = acc[mi][ni][r];
                if constexpr (EPI == 0) {
                    Cmat[(rowb + r) * N + col] = v;
                } else {
                    const int rowi = (int)(rowb + r);
                    const int b  = rowi >> 11;
                    const int t  = rowi & (T_ - 1);
                    const int coli = (int)col;
                    const int type = coli >> 10;
                    const int cc2  = coli & (C_ - 1);
                    const int h = cc2 >> 6, d = cc2 & (HD_ - 1);
                    const int bh = b * H_ + h;
                    if (type == 0)
                        qb[((size_t)bh * T_ + t) * HD_ + d] = __float2bfloat16(v * 0.125f);
                    else if (type == 1)
                        kb[((size_t)bh * T_ + t) * HD_ + d] = __float2bfloat16(v);
                    else
                        vb[((size_t)bh * HD_ + d) * T_ + t] = __float2bfloat16(v);
                }
            }
        }
    }
}

// ---------------------------------------------------------------------------
// Flash attention v3 (causal): BARRIER-FREE per-wave streaming.
// Each wave independently owns 32 Q-rows (heavy-first qtile mapping).
// K/V MFMA B-frags loaded DIRECTLY global->registers (16 B/lane coalesced).
// Softmax 16-lane reductions via DPP row_ror (VALU pipe, no DS traffic).
// Only LDS use: per-wave P transpose round-trip (wave-internal, no barrier).
// ---------------------------------------------------------------------------
#define PP 72

__global__ __launch_bounds__(256, 3)
void attn_wave(const bf16* __restrict__ qb, const bf16* __restrict__ kb,
               const bf16* __restrict__ vb, bf16* __restrict__ attn)
{
    __shared__ bf16 Plds[4][32][PP];     // 18.4 KB, per-wave region

    const int tid  = threadIdx.x;
    const int wave = tid >> 6, lane = tid & 63;
    const int quad = lane >> 4, l16 = lane & 15;
    const int bh   = blockIdx.y;
    const int qt   = (T_/32 - 1) - (blockIdx.x * 4 + wave);   // heavy waves first
    const int q0   = qt * 32;

    const bf16* Q  = qb + (size_t)bh * T_ * HD_;
    const bf16* Kp = kb + (size_t)bh * T_ * HD_;
    const bf16* Vp = vb + (size_t)bh * HD_ * T_;

    // Q frags [mi][kp]: A-layout m=l16, k=quad*8+j
    bf16x8v qf[2][2];
#pragma unroll
    for (int mi = 0; mi < 2; ++mi)
#pragma unroll
        for (int kp = 0; kp < 2; ++kp)
            qf[mi][kp] = *(const bf16x8v*)(Q + (size_t)(q0 + mi*16 + l16) * HD_ + kp*32 + quad*8);

    const f32x4 z4 = {0.f, 0.f, 0.f, 0.f};
    f32x4 o[2][4];
#pragma unroll
    for (int mi = 0; mi < 2; ++mi)
#pragma unroll
        for (int di = 0; di < 4; ++di) o[mi][di] = z4;
    float m_r[2][4], l_r[2][4];
#pragma unroll
    for (int mi = 0; mi < 2; ++mi)
#pragma unroll
        for (int r = 0; r < 4; ++r) { m_r[mi][r] = -3.0e38f; l_r[mi][r] = 0.f; }

    const int kend = q0 + 32;
    for (int k0 = 0; k0 < kend; k0 += 64) {
        // ---- K B-frags straight from global: [ni][kp], key n=l16, d k=quad*8+j ----
        bf16x8v kf[4][2];
#pragma unroll
        for (int ni = 0; ni < 4; ++ni)
#pragma unroll
            for (int kp = 0; kp < 2; ++kp)
                kf[ni][kp] = *(const bf16x8v*)(Kp + (size_t)(k0 + ni*16 + l16) * HD_ + kp*32 + quad*8);

        // ---- S = Q K^T ----
        f32x4 s[2][4];
#pragma unroll
        for (int mi = 0; mi < 2; ++mi)
#pragma unroll
            for (int ni = 0; ni < 4; ++ni) s[mi][ni] = z4;
#pragma unroll
        for (int kp = 0; kp < 2; ++kp)
#pragma unroll
            for (int ni = 0; ni < 4; ++ni) {
                s[0][ni] = mfma16(qf[0][kp], kf[ni][kp], s[0][ni]);
                s[1][ni] = mfma16(qf[1][kp], kf[ni][kp], s[1][ni]);
            }

        // ---- V B-frags from global (used after softmax; latency overlapped) ----
        bf16x8v vf[4][2];
#pragma unroll
        for (int di = 0; di < 4; ++di)
#pragma unroll
            for (int kp = 0; kp < 2; ++kp)
                vf[di][kp] = *(const bf16x8v*)(Vp + (size_t)(di*16 + l16) * T_ + k0 + kp*32 + quad*8);

        // ---- causal mask (only chunks straddling the diagonal) ----
        if (k0 + 63 > q0) {
#pragma unroll
            for (int mi = 0; mi < 2; ++mi)
#pragma unroll
                for (int r = 0; r < 4; ++r) {
                    const int row = q0 + mi*16 + quad*4 + r;
#pragma unroll
                    for (int ni = 0; ni < 4; ++ni)
                        if (k0 + ni*16 + l16 > row) s[mi][ni][r] = -3.0e38f;
                }
        }

        // ---- online softmax: DPP 16-lane reductions, rows = (mi,quad,r) ----
#pragma unroll
        for (int mi = 0; mi < 2; ++mi) {
#pragma unroll
            for (int r = 0; r < 4; ++r) {
                float mx = fmaxf(fmaxf(s[mi][0][r], s[mi][1][r]),
                                 fmaxf(s[mi][2][r], s[mi][3][r]));
                mx = row16_max(mx);
                const float mnew  = fmaxf(m_r[mi][r], mx);
                const float alpha = __expf(m_r[mi][r] - mnew);
                float e[4];
#pragma unroll
                for (int ni = 0; ni < 4; ++ni) e[ni] = __expf(s[mi][ni][r] - mnew);
                const float rsum = row16_sum((e[0] + e[1]) + (e[2] + e[3]));
                l_r[mi][r] = l_r[mi][r] * alpha + rsum;
                m_r[mi][r] = mnew;
#pragma unroll
                for (int di = 0; di < 4; ++di) o[mi][di][r] *= alpha;
                const int prow = mi*16 + quad*4 + r;
#pragma unroll
                for (int ni = 0; ni < 4; ++ni)
                    Plds[wave][prow][ni*16 + l16] = __float2bfloat16(e[ni]);
            }
        }

        // ---- P: C-layout -> A-layout via per-wave LDS (wave-internal order) ----
        bf16x8v pa[2][2];
#pragma unroll
        for (int mi = 0; mi < 2; ++mi)
#pragma unroll
            for (int kp = 0; kp < 2; ++kp)
                pa[mi][kp] = *(const bf16x8v*)(&Plds[wave][mi*16 + l16][kp*32 + quad*8]);

        // ---- O += P V ----
#pragma unroll
        for (int kp = 0; kp < 2; ++kp)
#pragma unroll
            for (int di = 0; di < 4; ++di) {
                o[0][di] = mfma16(pa[0][kp], vf[di][kp], o[0][di]);
                o[1][di] = mfma16(pa[1][kp], vf[di][kp], o[1][di]);
            }
    }

    // epilogue: attn[b][t][h*64+d], normalize by l
    const int b = bh >> 4, h = bh & (H_ - 1);
#pragma unroll
    for (int mi = 0; mi < 2; ++mi) {
#pragma unroll
        for (int r = 0; r < 4; ++r) {
            const float inv = 1.0f / l_r[mi][r];
            const int t = q0 + mi*16 + quad*4 + r;
            const size_t base = ((size_t)(b * T_ + t)) * C_ + h * HD_;
#pragma unroll
            for (int di = 0; di < 4; ++di)
                attn[base + di*16 + l16] = __float2bfloat16(o[mi][di][r] * inv);
        }
    }
}

// ---------------------------------------------------------------------------
// Workspace layout (MiB from d_ws), total 72 MiB:
//   [ 0,16)  q    bf16 [64][2048][64]  (pre-scaled 0.125)
//   [16,32)  k    bf16 [64][2048][64]
//   [32,48)  v    bf16 [64][64][2048]  (transposed [bh][d][t])
//   [48,64)  xb   bf16 [8192][1024]  -- aliased -> attnb (xb dead after GEMM1)
//   [64,70)  wt_qkv bf16 [3072][1024]
//   [70,72)  wt_out bf16 [1024][1024]
// ---------------------------------------------------------------------------
extern "C" void kernel_launch(void* const* d_in, const int* in_sizes, int n_in,
                              void* d_out, int out_size, void* d_ws, size_t ws_size,
                              hipStream_t stream)
{
    const float* x     = (const float*)d_in[0];
    const float* w_qkv = (const float*)d_in[1];
    const float* w_out = (const float*)d_in[2];
    float* out = (float*)d_out;

    char* ws = (char*)d_ws;
    bf16* qb     = (bf16*)(ws);
    bf16* kb     = (bf16*)(ws + (size_t)16 * 1024 * 1024);
    bf16* vb     = (bf16*)(ws + (size_t)32 * 1024 * 1024);
    bf16* xb     = (bf16*)(ws + (size_t)48 * 1024 * 1024);
    bf16* attnb  = xb;   // alias: xb consumed by GEMM1 before attn writes
    bf16* wtqkv  = (bf16*)(ws + (size_t)64 * 1024 * 1024);
    bf16* wtout  = (bf16*)(ws + (size_t)70 * 1024 * 1024);

    // 0) x -> bf16 (enables global_load_lds staging in GEMM1)
    convert_f32_bf16<<<dim3((M_*C_)/(8*256)), 256, 0, stream>>>(x, xb);

    // 1) weights -> bf16 transposed [N][K]
    transpose_f32_to_bf16<<<dim3(N1_/32, C_/32), 256, 0, stream>>>(w_qkv, wtqkv, C_, N1_);
    transpose_f32_to_bf16<<<dim3(C_/32,  C_/32), 256, 0, stream>>>(w_out, wtout, C_, C_);

    // 2) qkv = xb @ w_qkv, scatter q/k/v
    gemm_lds<1><<<dim3(N1_/128, M_/128), 256, 0, stream>>>(
        xb, wtqkv, nullptr, N1_, C_, qb, kb, vb);

    // 3) barrier-free causal flash attention
    attn_wave<<<dim3(T_/32/4, BH_), 256, 0, stream>>>(qb, kb, vb, attnb);

    // 4) out = attn @ w_out (fp32)
    gemm_lds<0><<<dim3(C_/128, M_/128), 256, 0, stream>>>(
        attnb, wtout, out, C_, C_, nullptr, nullptr, nullptr);
}

// Round 5
// 308.934 us; speedup vs baseline: 1.5385x; 1.5385x over previous
//
#include <hip/hip_runtime.h>
#include <hip/hip_bf16.h>

// Problem constants
#define B_   4
#define T_   2048
#define C_   1024
#define H_   16
#define HD_  64
#define BH_  (B_*H_)    // 64
#define M_   (B_*T_)    // 8192
#define N1_  (3*C_)     // 3072

typedef __hip_bfloat16 bf16;
typedef __attribute__((ext_vector_type(8))) __bf16 bf16x8v;   // MFMA A/B frag (4 VGPRs)
typedef __attribute__((ext_vector_type(4))) float  f32x4;     // MFMA C/D frag

__device__ __forceinline__ f32x4 mfma16(bf16x8v a, bf16x8v b, f32x4 c) {
    return __builtin_amdgcn_mfma_f32_16x16x32_bf16(a, b, c, 0, 0, 0);
}

// async global->LDS DMA, 16 B per lane (lds dest = wave-uniform base + lane*16)
typedef __attribute__((address_space(3))) unsigned int       lds_u32;
typedef const __attribute__((address_space(1))) unsigned int glb_u32;
__device__ __forceinline__ void async16(void* lds, const void* g) {
    __builtin_amdgcn_global_load_lds((glb_u32*)g, (lds_u32*)lds, 16, 0, 0);
}

// DPP 16-lane-row reductions (VALU pipe; verified r4: conflicts 5.4M -> 1.1M)
template<int CTRL>
__device__ __forceinline__ float dpp_rot(float x) {
    int v = __builtin_amdgcn_update_dpp(0, __float_as_int(x), CTRL, 0xF, 0xF, true);
    return __int_as_float(v);
}
__device__ __forceinline__ float row16_max(float x) {
    x = fmaxf(x, dpp_rot<0x121>(x));   // row_ror:1
    x = fmaxf(x, dpp_rot<0x122>(x));   // row_ror:2
    x = fmaxf(x, dpp_rot<0x124>(x));   // row_ror:4
    x = fmaxf(x, dpp_rot<0x128>(x));   // row_ror:8
    return x;
}
__device__ __forceinline__ float row16_sum(float x) {
    x += dpp_rot<0x121>(x);
    x += dpp_rot<0x122>(x);
    x += dpp_rot<0x124>(x);
    x += dpp_rot<0x128>(x);
    return x;
}

// ---------------------------------------------------------------------------
// fp32 -> bf16 elementwise convert (x), 8 elems/thread
// ---------------------------------------------------------------------------
__global__ void convert_f32_bf16(const float* __restrict__ in, bf16* __restrict__ out) {
    const int i = blockIdx.x * blockDim.x + threadIdx.x;
    float f[8];
    *(float4*)(f)     = ((const float4*)in)[i*2];
    *(float4*)(f + 4) = ((const float4*)in)[i*2 + 1];
    bf16 t[8];
#pragma unroll
    for (int j = 0; j < 8; ++j) t[j] = __float2bfloat16(f[j]);
    ((uint4*)out)[i] = *(uint4*)t;
}

// ---------------------------------------------------------------------------
// Tiled transpose + fp32->bf16 convert: out[n][k] = bf16(in[k][n]).
// ---------------------------------------------------------------------------
__global__ void transpose_f32_to_bf16(const float* __restrict__ in,
                                      bf16* __restrict__ out, int K, int N) {
    __shared__ float t[32][33];
    const int n0 = blockIdx.x * 32, k0 = blockIdx.y * 32;
    const int c  = threadIdx.x & 31;
    const int rr = threadIdx.x >> 5;
#pragma unroll
    for (int i = 0; i < 4; ++i)
        t[c][rr + 8*i] = in[(size_t)(k0 + rr + 8*i) * N + n0 + c];
    __syncthreads();
#pragma unroll
    for (int i = 0; i < 4; ++i)
        out[(size_t)(n0 + rr + 8*i) * K + k0 + c] = __float2bfloat16(t[rr + 8*i][c]);
}

// ---------------------------------------------------------------------------
// GEMM (m97 structure, unchanged from round 4 — it improved the GEMM stages):
// C[M,N] = A[M,K](bf16) @ Bt[N][K](bf16). 128x128 tile, BK=32,
// global_load_lds width=16 staging into unpadded [128][32] LDS.
// ---------------------------------------------------------------------------
template<int EPI>
__global__ __launch_bounds__(256, 2)
void gemm_lds(const bf16* __restrict__ A, const bf16* __restrict__ Bt,
              float* __restrict__ Cmat, int N, int K,
              bf16* __restrict__ qb, bf16* __restrict__ kb, bf16* __restrict__ vb)
{
    __shared__ bf16 Alds[128][32];
    __shared__ bf16 Blds[128][32];

    const int tid  = threadIdx.x;
    const int wave = tid >> 6, lane = tid & 63;
    const int quad = lane >> 4, l16 = lane & 15;
    const int wm   = (wave >> 1) * 64, wn = (wave & 1) * 64;
    const size_t row0 = (size_t)blockIdx.y * 128;
    const size_t col0 = (size_t)blockIdx.x * 128;

    const f32x4 z4 = {0.f, 0.f, 0.f, 0.f};
    f32x4 acc[4][4];
#pragma unroll
    for (int mi = 0; mi < 4; ++mi)
#pragma unroll
        for (int ni = 0; ni < 4; ++ni) acc[mi][ni] = z4;

    const int sr = lane >> 2;
    const int sc = (lane & 3) * 8;
    const bf16* gA0 = A  + (row0 + wave*32 + sr) * (size_t)K + sc;
    const bf16* gA1 = gA0 + (size_t)16 * K;
    const bf16* gB0 = Bt + (col0 + wave*32 + sr) * (size_t)K + sc;
    const bf16* gB1 = gB0 + (size_t)16 * K;
    bf16* lA0 = &Alds[wave*32][0];
    bf16* lA1 = &Alds[wave*32 + 16][0];
    bf16* lB0 = &Blds[wave*32][0];
    bf16* lB1 = &Blds[wave*32 + 16][0];

    for (int k0 = 0; k0 < K; k0 += 32) {
        async16(lA0, gA0 + k0);
        async16(lA1, gA1 + k0);
        async16(lB0, gB0 + k0);
        async16(lB1, gB1 + k0);
        __syncthreads();

        bf16x8v af[4], bfr[4];
#pragma unroll
        for (int i = 0; i < 4; ++i) {
            af[i]  = *(const bf16x8v*)(&Alds[wm + i*16 + l16][quad*8]);
            bfr[i] = *(const bf16x8v*)(&Blds[wn + i*16 + l16][quad*8]);
        }
#pragma unroll
        for (int mi = 0; mi < 4; ++mi)
#pragma unroll
            for (int ni = 0; ni < 4; ++ni)
                acc[mi][ni] = mfma16(af[mi], bfr[ni], acc[mi][ni]);
        __syncthreads();
    }

#pragma unroll
    for (int mi = 0; mi < 4; ++mi) {
        const size_t rowb = row0 + wm + mi*16 + quad*4;
#pragma unroll
        for (int ni = 0; ni < 4; ++ni) {
            const size_t col = col0 + wn + ni*16 + l16;
#pragma unroll
            for (int r = 0; r < 4; ++r) {
                const float v = acc[mi][ni][r];
                if constexpr (EPI == 0) {
                    Cmat[(rowb + r) * N + col] = v;
                } else {
                    const int rowi = (int)(rowb + r);
                    const int b  = rowi >> 11;
                    const int t  = rowi & (T_ - 1);
                    const int coli = (int)col;
                    const int type = coli >> 10;
                    const int cc2  = coli & (C_ - 1);
                    const int h = cc2 >> 6, d = cc2 & (HD_ - 1);
                    const int bh = b * H_ + h;
                    if (type == 0)
                        qb[((size_t)bh * T_ + t) * HD_ + d] = __float2bfloat16(v * 0.125f);
                    else if (type == 1)
                        kb[((size_t)bh * T_ + t) * HD_ + d] = __float2bfloat16(v);
                    else
                        vb[((size_t)bh * HD_ + d) * T_ + t] = __float2bfloat16(v);
                }
            }
        }
    }
}

// ---------------------------------------------------------------------------
// Flash attention v4 (causal): v2 structure (block-shared LDS K/V staging,
// register prefetch) + PAIRED Q-TILES for uniform work + DPP softmax.
// Block handles q-tiles {bx, 15-bx} (128 rows each) -> every block does
// exactly 34 chunk-iterations. grid = (8, 64) = 512 uniform blocks.
// 4 waves/block, each wave 32 rows (2 m-frags); KV chunk = 64 keys.
// ---------------------------------------------------------------------------
#define KP 72   // 64+8
#define VP 72
#define PP 72

__global__ __launch_bounds__(256, 2)
void attn_pair(const bf16* __restrict__ qb, const bf16* __restrict__ kb,
               const bf16* __restrict__ vb, bf16* __restrict__ attn)
{
    __shared__ bf16 Klds[64][KP];        // 9.2 KB   K[key][d]
    __shared__ bf16 Vlds[64][VP];        // 9.2 KB   V[d][key]
    __shared__ bf16 Plds[4][32][PP];     // 18.4 KB  per-wave P round-trip

    const int tid  = threadIdx.x;
    const int wave = tid >> 6, lane = tid & 63;
    const int quad = lane >> 4, l16 = lane & 15;
    const int bh   = blockIdx.y;

    const bf16* Q  = qb + (size_t)bh * T_ * HD_;
    const bf16* Kp = kb + (size_t)bh * T_ * HD_;
    const bf16* Vp = vb + (size_t)bh * HD_ * T_;

    // staging: thread covers K rows {kr, kr+32} cols kc..kc+7; V d-rows same
    const int kr = tid >> 3;          // 0..31
    const int kc = (tid & 7) * 8;     // 0..56

    const int b = bh >> 4, h = bh & (H_ - 1);
    const f32x4 z4 = {0.f, 0.f, 0.f, 0.f};

    const int tiles[2] = { (int)blockIdx.x, 15 - (int)blockIdx.x };

#pragma unroll 1
    for (int tt = 0; tt < 2; ++tt) {
        const int q0b = tiles[tt] * 128;
        const int q0w = q0b + wave * 32;

        // Q frags [mi][kp]: A-layout m=l16, k=quad*8+j
        bf16x8v qf[2][2];
#pragma unroll
        for (int mi = 0; mi < 2; ++mi)
#pragma unroll
            for (int kp = 0; kp < 2; ++kp)
                qf[mi][kp] = *(const bf16x8v*)(Q + (size_t)(q0w + mi*16 + l16) * HD_ + kp*32 + quad*8);

        f32x4 o[2][4];
#pragma unroll
        for (int mi = 0; mi < 2; ++mi)
#pragma unroll
            for (int di = 0; di < 4; ++di) o[mi][di] = z4;
        float m_r[2][4], l_r[2][4];
#pragma unroll
        for (int mi = 0; mi < 2; ++mi)
#pragma unroll
            for (int r = 0; r < 4; ++r) { m_r[mi][r] = -3.0e38f; l_r[mi][r] = 0.f; }

        const int kend = q0b + 128;

        // preload chunk 0
        uint4 kreg0 = *(const uint4*)(Kp + (size_t)kr        * HD_ + kc);
        uint4 kreg1 = *(const uint4*)(Kp + (size_t)(kr + 32) * HD_ + kc);
        uint4 vreg0 = *(const uint4*)(Vp + (size_t)kr        * T_  + kc);
        uint4 vreg1 = *(const uint4*)(Vp + (size_t)(kr + 32) * T_  + kc);

        for (int k0 = 0; k0 < kend; k0 += 64) {
            __syncthreads();   // prior chunk's LDS reads complete
            *(uint4*)(&Klds[kr][kc])      = kreg0;
            *(uint4*)(&Klds[kr + 32][kc]) = kreg1;
            *(uint4*)(&Vlds[kr][kc])      = vreg0;
            *(uint4*)(&Vlds[kr + 32][kc]) = vreg1;
            __syncthreads();

            // prefetch next chunk into registers (in flight during compute)
            const int kn = (k0 + 64 < kend) ? (k0 + 64) : k0;
            kreg0 = *(const uint4*)(Kp + (size_t)(kn + kr)      * HD_ + kc);
            kreg1 = *(const uint4*)(Kp + (size_t)(kn + kr + 32) * HD_ + kc);
            vreg0 = *(const uint4*)(Vp + (size_t)kr        * T_ + kn + kc);
            vreg1 = *(const uint4*)(Vp + (size_t)(kr + 32) * T_ + kn + kc);

            if (k0 <= q0w + 31) {   // wave-uniform causal skip
                // ---- S = Q K^T : 2 m-tiles x 4 n-tiles ----
                f32x4 s[2][4];
#pragma unroll
                for (int mi = 0; mi < 2; ++mi)
#pragma unroll
                    for (int ni = 0; ni < 4; ++ni) s[mi][ni] = z4;
#pragma unroll
                for (int kp = 0; kp < 2; ++kp) {
#pragma unroll
                    for (int ni = 0; ni < 4; ++ni) {
                        const bf16x8v kf = *(const bf16x8v*)(&Klds[ni*16 + l16][kp*32 + quad*8]);
                        s[0][ni] = mfma16(qf[0][kp], kf, s[0][ni]);
                        s[1][ni] = mfma16(qf[1][kp], kf, s[1][ni]);
                    }
                }
                // ---- causal mask (only chunks straddling the diagonal) ----
                if (k0 + 63 > q0w) {
#pragma unroll
                    for (int mi = 0; mi < 2; ++mi)
#pragma unroll
                        for (int r = 0; r < 4; ++r) {
                            const int row = q0w + mi*16 + quad*4 + r;
#pragma unroll
                            for (int ni = 0; ni < 4; ++ni)
                                if (k0 + ni*16 + l16 > row) s[mi][ni][r] = -3.0e38f;
                        }
                }
                // ---- online softmax: DPP 16-lane reductions ----
#pragma unroll
                for (int mi = 0; mi < 2; ++mi) {
#pragma unroll
                    for (int r = 0; r < 4; ++r) {
                        float mx = fmaxf(fmaxf(s[mi][0][r], s[mi][1][r]),
                                         fmaxf(s[mi][2][r], s[mi][3][r]));
                        mx = row16_max(mx);
                        const float mnew  = fmaxf(m_r[mi][r], mx);
                        const float alpha = __expf(m_r[mi][r] - mnew);
                        float e[4];
#pragma unroll
                        for (int ni = 0; ni < 4; ++ni) e[ni] = __expf(s[mi][ni][r] - mnew);
                        const float rsum = row16_sum((e[0] + e[1]) + (e[2] + e[3]));
                        l_r[mi][r] = l_r[mi][r] * alpha + rsum;
                        m_r[mi][r] = mnew;
#pragma unroll
                        for (int di = 0; di < 4; ++di) o[mi][di][r] *= alpha;
                        const int prow = mi*16 + quad*4 + r;
#pragma unroll
                        for (int ni = 0; ni < 4; ++ni)
                            Plds[wave][prow][ni*16 + l16] = __float2bfloat16(e[ni]);
                    }
                }
                // ---- P: C-layout -> A-layout (wave-internal LDS, no barrier) ----
                bf16x8v pa[2][2];
#pragma unroll
                for (int mi = 0; mi < 2; ++mi)
#pragma unroll
                    for (int kp = 0; kp < 2; ++kp)
                        pa[mi][kp] = *(const bf16x8v*)(&Plds[wave][mi*16 + l16][kp*32 + quad*8]);
                // ---- O += P V ----
#pragma unroll
                for (int kp = 0; kp < 2; ++kp)
#pragma unroll
                    for (int di = 0; di < 4; ++di) {
                        const bf16x8v vf = *(const bf16x8v*)(&Vlds[di*16 + l16][kp*32 + quad*8]);
                        o[0][di] = mfma16(pa[0][kp], vf, o[0][di]);
                        o[1][di] = mfma16(pa[1][kp], vf, o[1][di]);
                    }
            }
        }

        // epilogue: attn[b][t][h*64+d], normalize by l
#pragma unroll
        for (int mi = 0; mi < 2; ++mi) {
#pragma unroll
            for (int r = 0; r < 4; ++r) {
                const float inv = 1.0f / l_r[mi][r];
                const int t = q0w + mi*16 + quad*4 + r;
                const size_t base = ((size_t)(b * T_ + t)) * C_ + h * HD_;
#pragma unroll
                for (int di = 0; di < 4; ++di)
                    attn[base + di*16 + l16] = __float2bfloat16(o[mi][di][r] * inv);
            }
        }
    }
}

// ---------------------------------------------------------------------------
// Workspace layout (MiB from d_ws), total 72 MiB:
//   [ 0,16)  q    bf16 [64][2048][64]  (pre-scaled 0.125)
//   [16,32)  k    bf16 [64][2048][64]
//   [32,48)  v    bf16 [64][64][2048]  (transposed [bh][d][t])
//   [48,64)  xb   bf16 [8192][1024]  -- aliased -> attnb (xb dead after GEMM1)
//   [64,70)  wt_qkv bf16 [3072][1024]
//   [70,72)  wt_out bf16 [1024][1024]
// ---------------------------------------------------------------------------
extern "C" void kernel_launch(void* const* d_in, const int* in_sizes, int n_in,
                              void* d_out, int out_size, void* d_ws, size_t ws_size,
                              hipStream_t stream)
{
    const float* x     = (const float*)d_in[0];
    const float* w_qkv = (const float*)d_in[1];
    const float* w_out = (const float*)d_in[2];
    float* out = (float*)d_out;

    char* ws = (char*)d_ws;
    bf16* qb     = (bf16*)(ws);
    bf16* kb     = (bf16*)(ws + (size_t)16 * 1024 * 1024);
    bf16* vb     = (bf16*)(ws + (size_t)32 * 1024 * 1024);
    bf16* xb     = (bf16*)(ws + (size_t)48 * 1024 * 1024);
    bf16* attnb  = xb;   // alias: xb consumed by GEMM1 before attn writes
    bf16* wtqkv  = (bf16*)(ws + (size_t)64 * 1024 * 1024);
    bf16* wtout  = (bf16*)(ws + (size_t)70 * 1024 * 1024);

    // 0) x -> bf16 (enables global_load_lds staging in GEMM1)
    convert_f32_bf16<<<dim3((M_*C_)/(8*256)), 256, 0, stream>>>(x, xb);

    // 1) weights -> bf16 transposed [N][K]
    transpose_f32_to_bf16<<<dim3(N1_/32, C_/32), 256, 0, stream>>>(w_qkv, wtqkv, C_, N1_);
    transpose_f32_to_bf16<<<dim3(C_/32,  C_/32), 256, 0, stream>>>(w_out, wtout, C_, C_);

    // 2) qkv = xb @ w_qkv, scatter q/k/v
    gemm_lds<1><<<dim3(N1_/128, M_/128), 256, 0, stream>>>(
        xb, wtqkv, nullptr, N1_, C_, qb, kb, vb);

    // 3) causal flash attention, paired-tile balanced
    attn_pair<<<dim3(8, BH_), 256, 0, stream>>>(qb, kb, vb, attnb);

    // 4) out = attn @ w_out (fp32)
    gemm_lds<0><<<dim3(C_/128, M_/128), 256, 0, stream>>>(
        attnb, wtout, out, C_, C_, nullptr, nullptr, nullptr);
}

// Round 7
// 265.698 us; speedup vs baseline: 1.7888x; 1.1627x over previous
//
#include <hip/hip_runtime.h>
#include <hip/hip_bf16.h>

// Problem constants
#define B_   4
#define T_   2048
#define C_   1024
#define H_   16
#define HD_  64
#define BH_  (B_*H_)    // 64
#define M_   (B_*T_)    // 8192
#define N1_  (3*C_)     // 3072

typedef __hip_bfloat16 bf16;
typedef __attribute__((ext_vector_type(8))) __bf16 bf16x8v;   // MFMA A/B frag (4 VGPRs)
typedef __attribute__((ext_vector_type(4))) float  f32x4;     // MFMA C/D frag

// Q pre-scale: 1/sqrt(64) * log2(e)  -> softmax computed with exp2 (1 v_exp_f32)
#define QSCALE 0.18033688f

__device__ __forceinline__ f32x4 mfma16(bf16x8v a, bf16x8v b, f32x4 c) {
    return __builtin_amdgcn_mfma_f32_16x16x32_bf16(a, b, c, 0, 0, 0);
}

// exp2 on the VALU transcendental pipe (v_exp_f32 computes 2^x natively)
__device__ __forceinline__ float exp2_hw(float x) {
    return __builtin_amdgcn_exp2f(x);
}

// async global->LDS DMA, 16 B per lane (lds dest = wave-uniform base + lane*16)
typedef __attribute__((address_space(3))) unsigned int       lds_u32;
typedef const __attribute__((address_space(1))) unsigned int glb_u32;
__device__ __forceinline__ void async16(void* lds, const void* g) {
    __builtin_amdgcn_global_load_lds((glb_u32*)g, (lds_u32*)lds, 16, 0, 0);
}

// DPP 16-lane-row reduction (VALU pipe)
template<int CTRL>
__device__ __forceinline__ float dpp_rot(float x) {
    int v = __builtin_amdgcn_update_dpp(0, __float_as_int(x), CTRL, 0xF, 0xF, true);
    return __int_as_float(v);
}
__device__ __forceinline__ float row16_sum(float x) {
    x += dpp_rot<0x121>(x);   // row_ror:1
    x += dpp_rot<0x122>(x);   // row_ror:2
    x += dpp_rot<0x124>(x);   // row_ror:4
    x += dpp_rot<0x128>(x);   // row_ror:8
    return x;
}

// ---------------------------------------------------------------------------
// fp32 -> bf16 elementwise convert (x), 8 elems/thread
// ---------------------------------------------------------------------------
__global__ void convert_f32_bf16(const float* __restrict__ in, bf16* __restrict__ out) {
    const int i = blockIdx.x * blockDim.x + threadIdx.x;
    float f[8];
    *(float4*)(f)     = ((const float4*)in)[i*2];
    *(float4*)(f + 4) = ((const float4*)in)[i*2 + 1];
    bf16 t[8];
#pragma unroll
    for (int j = 0; j < 8; ++j) t[j] = __float2bfloat16(f[j]);
    ((uint4*)out)[i] = *(uint4*)t;
}

// ---------------------------------------------------------------------------
// Tiled transpose + fp32->bf16 convert: out[n][k] = bf16(in[k][n]).
// ---------------------------------------------------------------------------
__global__ void transpose_f32_to_bf16(const float* __restrict__ in,
                                      bf16* __restrict__ out, int K, int N) {
    __shared__ float t[32][33];
    const int n0 = blockIdx.x * 32, k0 = blockIdx.y * 32;
    const int c  = threadIdx.x & 31;
    const int rr = threadIdx.x >> 5;
#pragma unroll
    for (int i = 0; i < 4; ++i)
        t[c][rr + 8*i] = in[(size_t)(k0 + rr + 8*i) * N + n0 + c];
    __syncthreads();
#pragma unroll
    for (int i = 0; i < 4; ++i)
        out[(size_t)(n0 + rr + 8*i) * K + k0 + c] = __float2bfloat16(t[rr + 8*i][c]);
}

// ---------------------------------------------------------------------------
// GEMM (m97 structure + XOR-swizzled LDS): C[M,N] = A(bf16)[M,K] @ Bt(bf16)[N,K].
// 128x128 tile, BK=32, global_load_lds width=16 into unpadded [128][32].
// Swizzle: LDS granule g' of row r holds global 8-elem granule g'^((r>>1)&3);
// DMA lanes pre-permute the GLOBAL fetch (wave-uniform LDS dest preserved),
// frag reads use granule quad^((l16>>1)&3) -> 8-way conflicts become 2-way.
// ---------------------------------------------------------------------------
template<int EPI>
__global__ __launch_bounds__(256, 2)
void gemm_lds(const bf16* __restrict__ A, const bf16* __restrict__ Bt,
              float* __restrict__ Cmat, int N, int K,
              bf16* __restrict__ qb, bf16* __restrict__ kb, bf16* __restrict__ vb)
{
    __shared__ bf16 Alds[128][32];
    __shared__ bf16 Blds[128][32];

    const int tid  = threadIdx.x;
    const int wave = tid >> 6, lane = tid & 63;
    const int quad = lane >> 4, l16 = lane & 15;
    const int wm   = (wave >> 1) * 64, wn = (wave & 1) * 64;
    const size_t row0 = (size_t)blockIdx.y * 128;
    const size_t col0 = (size_t)blockIdx.x * 128;

    const f32x4 z4 = {0.f, 0.f, 0.f, 0.f};
    f32x4 acc[4][4];
#pragma unroll
    for (int mi = 0; mi < 4; ++mi)
#pragma unroll
        for (int ni = 0; ni < 4; ++ni) acc[mi][ni] = z4;

    // staging: lane -> row sr (=lane>>2), SWIZZLED global granule
    const int sr = lane >> 2;
    const int sc = (((lane & 3) ^ ((lane >> 3) & 3))) * 8;   // granule ^ key(row)
    const bf16* gA0 = A  + (row0 + wave*32 + sr) * (size_t)K + sc;
    const bf16* gA1 = gA0 + (size_t)16 * K;
    const bf16* gB0 = Bt + (col0 + wave*32 + sr) * (size_t)K + sc;
    const bf16* gB1 = gB0 + (size_t)16 * K;
    bf16* lA0 = &Alds[wave*32][0];
    bf16* lA1 = &Alds[wave*32 + 16][0];
    bf16* lB0 = &Blds[wave*32][0];
    bf16* lB1 = &Blds[wave*32 + 16][0];

    // frag-read swizzled granule offset (elements)
    const int fg = (quad ^ ((l16 >> 1) & 3)) * 8;

    for (int k0 = 0; k0 < K; k0 += 32) {
        async16(lA0, gA0 + k0);
        async16(lA1, gA1 + k0);
        async16(lB0, gB0 + k0);
        async16(lB1, gB1 + k0);
        __syncthreads();

        bf16x8v af[4], bfr[4];
#pragma unroll
        for (int i = 0; i < 4; ++i) {
            af[i]  = *(const bf16x8v*)(&Alds[wm + i*16 + l16][fg]);
            bfr[i] = *(const bf16x8v*)(&Blds[wn + i*16 + l16][fg]);
        }
#pragma unroll
        for (int mi = 0; mi < 4; ++mi)
#pragma unroll
            for (int ni = 0; ni < 4; ++ni)
                acc[mi][ni] = mfma16(af[mi], bfr[ni], acc[mi][ni]);
        __syncthreads();
    }

#pragma unroll
    for (int mi = 0; mi < 4; ++mi) {
        const size_t rowb = row0 + wm + mi*16 + quad*4;
#pragma unroll
        for (int ni = 0; ni < 4; ++ni) {
            const size_t col = col0 + wn + ni*16 + l16;
#pragma unroll
            for (int r = 0; r < 4; ++r) {
                const float v = acc[mi][ni][r];
                if constexpr (EPI == 0) {
                    Cmat[(rowb + r) * N + col] = v;
                } else {
                    const int rowi = (int)(rowb + r);
                    const int b  = rowi >> 11;
                    const int t  = rowi & (T_ - 1);
                    const int coli = (int)col;
                    const int type = coli >> 10;
                    const int cc2  = coli & (C_ - 1);
                    const int h = cc2 >> 6, d = cc2 & (HD_ - 1);
                    const int bh = b * H_ + h;
                    if (type == 0)
                        qb[((size_t)bh * T_ + t) * HD_ + d] = __float2bfloat16(v * QSCALE);
                    else if (type == 1)
                        kb[((size_t)bh * T_ + t) * HD_ + d] = __float2bfloat16(v);
                    else
                        vb[((size_t)bh * HD_ + d) * T_ + t] = __float2bfloat16(v);
                }
            }
        }
    }
}

// ---------------------------------------------------------------------------
// Flash attention v5 (causal): paired q-tiles {bx,15-bx} (uniform 34 iters),
// double-buffered K/V LDS (ONE barrier per chunk), register prefetch across
// tile boundary, STATIC-MAX softmax in log2 domain:
//   P = exp2(s_log2)   (Q pre-scaled by 0.125*log2e; no running max, no
//   alpha rescale — scores bounded ~|30| << exp2 overflow at 128),
// per-lane l partials, single DPP reduction in epilogue.
// ---------------------------------------------------------------------------
#define KP 72   // 64+8
#define VP 72
#define PP 72

__global__ __launch_bounds__(256, 2)
void attn_pair(const bf16* __restrict__ qb, const bf16* __restrict__ kb,
               const bf16* __restrict__ vb, bf16* __restrict__ attn)
{
    __shared__ bf16 Klds[2][64][KP];     // 18.4 KB  K[key][d]
    __shared__ bf16 Vlds[2][64][VP];     // 18.4 KB  V[d][key]
    __shared__ bf16 Plds[4][32][PP];     // 18.4 KB  per-wave P round-trip

    const int tid  = threadIdx.x;
    const int wave = tid >> 6, lane = tid & 63;
    const int quad = lane >> 4, l16 = lane & 15;
    const int bh   = blockIdx.y;

    const bf16* Q  = qb + (size_t)bh * T_ * HD_;
    const bf16* Kp = kb + (size_t)bh * T_ * HD_;
    const bf16* Vp = vb + (size_t)bh * HD_ * T_;

    const int kr = tid >> 3;          // 0..31
    const int kc = (tid & 7) * 8;     // 0..56

    const int b = bh >> 4, h = bh & (H_ - 1);
    const f32x4 z4 = {0.f, 0.f, 0.f, 0.f};

    const int tiles[2] = { (int)blockIdx.x, 15 - (int)blockIdx.x };

    // preload chunk 0 (keys 0..63) — shared key-space across both tiles
    uint4 kreg0 = *(const uint4*)(Kp + (size_t)kr        * HD_ + kc);
    uint4 kreg1 = *(const uint4*)(Kp + (size_t)(kr + 32) * HD_ + kc);
    uint4 vreg0 = *(const uint4*)(Vp + (size_t)kr        * T_  + kc);
    uint4 vreg1 = *(const uint4*)(Vp + (size_t)(kr + 32) * T_  + kc);

    int p = 0;   // LDS buffer parity (runs continuously across both tiles)

#pragma unroll 1
    for (int tt = 0; tt < 2; ++tt) {
        const int q0b = tiles[tt] * 128;
        const int q0w = q0b + wave * 32;

        bf16x8v qf[2][2];
#pragma unroll
        for (int mi = 0; mi < 2; ++mi)
#pragma unroll
            for (int kp = 0; kp < 2; ++kp)
                qf[mi][kp] = *(const bf16x8v*)(Q + (size_t)(q0w + mi*16 + l16) * HD_ + kp*32 + quad*8);

        f32x4 o[2][4];
#pragma unroll
        for (int mi = 0; mi < 2; ++mi)
#pragma unroll
            for (int di = 0; di < 4; ++di) o[mi][di] = z4;
        float l_r[2][4];
#pragma unroll
        for (int mi = 0; mi < 2; ++mi)
#pragma unroll
            for (int r = 0; r < 4; ++r) l_r[mi][r] = 0.f;

        const int kend = q0b + 128;

#pragma unroll 1
        for (int k0 = 0; k0 < kend; k0 += 64) {
            // stage prefetched regs into buffer p (prior reads of p were 2
            // chunk-iters ago, guaranteed complete past the last barrier)
            *(uint4*)(&Klds[p][kr][kc])      = kreg0;
            *(uint4*)(&Klds[p][kr + 32][kc]) = kreg1;
            *(uint4*)(&Vlds[p][kr][kc])      = vreg0;
            *(uint4*)(&Vlds[p][kr + 32][kc]) = vreg1;
            __syncthreads();   // single barrier per chunk

            // prefetch next chunk (or next tile's chunk 0) — in flight during compute
            const int kn = (k0 + 64 < kend) ? (k0 + 64) : 0;
            kreg0 = *(const uint4*)(Kp + (size_t)(kn + kr)      * HD_ + kc);
            kreg1 = *(const uint4*)(Kp + (size_t)(kn + kr + 32) * HD_ + kc);
            vreg0 = *(const uint4*)(Vp + (size_t)kr        * T_ + kn + kc);
            vreg1 = *(const uint4*)(Vp + (size_t)(kr + 32) * T_ + kn + kc);

            if (k0 <= q0w + 31) {   // wave-uniform causal skip
                // ---- S = Q K^T (scores already in log2 domain) ----
                f32x4 s[2][4];
#pragma unroll
                for (int mi = 0; mi < 2; ++mi)
#pragma unroll
                    for (int ni = 0; ni < 4; ++ni) s[mi][ni] = z4;
#pragma unroll
                for (int kp = 0; kp < 2; ++kp) {
#pragma unroll
                    for (int ni = 0; ni < 4; ++ni) {
                        const bf16x8v kf = *(const bf16x8v*)(&Klds[p][ni*16 + l16][kp*32 + quad*8]);
                        s[0][ni] = mfma16(qf[0][kp], kf, s[0][ni]);
                        s[1][ni] = mfma16(qf[1][kp], kf, s[1][ni]);
                    }
                }
                // ---- causal mask (chunks straddling the diagonal only) ----
                if (k0 + 63 > q0w) {
#pragma unroll
                    for (int mi = 0; mi < 2; ++mi)
#pragma unroll
                        for (int r = 0; r < 4; ++r) {
                            const int row = q0w + mi*16 + quad*4 + r;
#pragma unroll
                            for (int ni = 0; ni < 4; ++ni)
                                if (k0 + ni*16 + l16 > row) s[mi][ni][r] = -3.0e38f;
                        }
                }
                // ---- static-max softmax: P = exp2(s); l accumulates per-lane ----
#pragma unroll
                for (int mi = 0; mi < 2; ++mi) {
#pragma unroll
                    for (int r = 0; r < 4; ++r) {
                        float e[4];
#pragma unroll
                        for (int ni = 0; ni < 4; ++ni) e[ni] = exp2_hw(s[mi][ni][r]);
                        l_r[mi][r] += (e[0] + e[1]) + (e[2] + e[3]);
                        const int prow = mi*16 + quad*4 + r;
#pragma unroll
                        for (int ni = 0; ni < 4; ++ni)
                            Plds[wave][prow][ni*16 + l16] = __float2bfloat16(e[ni]);
                    }
                }
                // ---- P: C-layout -> A-layout (wave-internal LDS, no barrier) ----
                bf16x8v pa[2][2];
#pragma unroll
                for (int mi = 0; mi < 2; ++mi)
#pragma unroll
                    for (int kp = 0; kp < 2; ++kp)
                        pa[mi][kp] = *(const bf16x8v*)(&Plds[wave][mi*16 + l16][kp*32 + quad*8]);
                // ---- O += P V (no rescale — static max) ----
#pragma unroll
                for (int kp = 0; kp < 2; ++kp)
#pragma unroll
                    for (int di = 0; di < 4; ++di) {
                        const bf16x8v vf = *(const bf16x8v*)(&Vlds[p][di*16 + l16][kp*32 + quad*8]);
                        o[0][di] = mfma16(pa[0][kp], vf, o[0][di]);
                        o[1][di] = mfma16(pa[1][kp], vf, o[1][di]);
                    }
            }
            p ^= 1;
        }

        // epilogue: one DPP row-reduction for l, normalize, store
#pragma unroll
        for (int mi = 0; mi < 2; ++mi) {
#pragma unroll
            for (int r = 0; r < 4; ++r) {
                const float inv = 1.0f / row16_sum(l_r[mi][r]);
                const int t = q0w + mi*16 + quad*4 + r;
                const size_t base = ((size_t)(b * T_ + t)) * C_ + h * HD_;
#pragma unroll
                for (int di = 0; di < 4; ++di)
                    attn[base + di*16 + l16] = __float2bfloat16(o[mi][di][r] * inv);
            }
        }
    }
}

// ---------------------------------------------------------------------------
// Workspace layout (MiB from d_ws), total 72 MiB:
//   [ 0,16)  q    bf16 [64][2048][64]  (pre-scaled 0.125*log2e)
//   [16,32)  k    bf16 [64][2048][64]
//   [32,48)  v    bf16 [64][64][2048]  (transposed [bh][d][t])
//   [48,64)  xb   bf16 [8192][1024]  -- aliased -> attnb (xb dead after GEMM1)
//   [64,70)  wt_qkv bf16 [3072][1024]
//   [70,72)  wt_out bf16 [1024][1024]
// ---------------------------------------------------------------------------
extern "C" void kernel_launch(void* const* d_in, const int* in_sizes, int n_in,
                              void* d_out, int out_size, void* d_ws, size_t ws_size,
                              hipStream_t stream)
{
    const float* x     = (const float*)d_in[0];
    const float* w_qkv = (const float*)d_in[1];
    const float* w_out = (const float*)d_in[2];
    float* out = (float*)d_out;

    char* ws = (char*)d_ws;
    bf16* qb     = (bf16*)(ws);
    bf16* kb     = (bf16*)(ws + (size_t)16 * 1024 * 1024);
    bf16* vb     = (bf16*)(ws + (size_t)32 * 1024 * 1024);
    bf16* xb     = (bf16*)(ws + (size_t)48 * 1024 * 1024);
    bf16* attnb  = xb;   // alias: xb consumed by GEMM1 before attn writes
    bf16* wtqkv  = (bf16*)(ws + (size_t)64 * 1024 * 1024);
    bf16* wtout  = (bf16*)(ws + (size_t)70 * 1024 * 1024);

    // 0) x -> bf16 (enables global_load_lds staging in GEMM1)
    convert_f32_bf16<<<dim3((M_*C_)/(8*256)), 256, 0, stream>>>(x, xb);

    // 1) weights -> bf16 transposed [N][K]
    transpose_f32_to_bf16<<<dim3(N1_/32, C_/32), 256, 0, stream>>>(w_qkv, wtqkv, C_, N1_);
    transpose_f32_to_bf16<<<dim3(C_/32,  C_/32), 256, 0, stream>>>(w_out, wtout, C_, C_);

    // 2) qkv = xb @ w_qkv, scatter q/k/v
    gemm_lds<1><<<dim3(N1_/128, M_/128), 256, 0, stream>>>(
        xb, wtqkv, nullptr, N1_, C_, qb, kb, vb);

    // 3) causal flash attention, paired-tile balanced, static-max softmax
    attn_pair<<<dim3(8, BH_), 256, 0, stream>>>(qb, kb, vb, attnb);

    // 4) out = attn @ w_out (fp32)
    gemm_lds<0><<<dim3(C_/128, M_/128), 256, 0, stream>>>(
        attnb, wtout, out, C_, C_, nullptr, nullptr, nullptr);
}

// Round 8
// 251.084 us; speedup vs baseline: 1.8930x; 1.0582x over previous
//
#include <hip/hip_runtime.h>
#include <hip/hip_bf16.h>

// Problem constants
#define B_   4
#define T_   2048
#define C_   1024
#define H_   16
#define HD_  64
#define BH_  (B_*H_)    // 64
#define M_   (B_*T_)    // 8192
#define N1_  (3*C_)     // 3072

typedef __hip_bfloat16 bf16;
typedef __attribute__((ext_vector_type(8))) __bf16 bf16x8v;   // MFMA A/B frag (4 VGPRs)
typedef __attribute__((ext_vector_type(4))) float  f32x4;     // MFMA C/D frag

// Q pre-scale: 1/sqrt(64) * log2(e)  -> softmax computed with exp2 (1 v_exp_f32)
#define QSCALE 0.18033688f

__device__ __forceinline__ f32x4 mfma16(bf16x8v a, bf16x8v b, f32x4 c) {
    return __builtin_amdgcn_mfma_f32_16x16x32_bf16(a, b, c, 0, 0, 0);
}

// exp2 on the VALU transcendental pipe (v_exp_f32 computes 2^x natively)
__device__ __forceinline__ float exp2_hw(float x) {
    return __builtin_amdgcn_exp2f(x);
}

// async global->LDS DMA, 16 B per lane (lds dest = wave-uniform base + lane*16)
typedef __attribute__((address_space(3))) unsigned int       lds_u32;
typedef const __attribute__((address_space(1))) unsigned int glb_u32;
__device__ __forceinline__ void async16(void* lds, const void* g) {
    __builtin_amdgcn_global_load_lds((glb_u32*)g, (lds_u32*)lds, 16, 0, 0);
}

// ---------------------------------------------------------------------------
// fp32 -> bf16 elementwise convert (x), 8 elems/thread
// ---------------------------------------------------------------------------
__global__ void convert_f32_bf16(const float* __restrict__ in, bf16* __restrict__ out) {
    const int i = blockIdx.x * blockDim.x + threadIdx.x;
    float f[8];
    *(float4*)(f)     = ((const float4*)in)[i*2];
    *(float4*)(f + 4) = ((const float4*)in)[i*2 + 1];
    bf16 t[8];
#pragma unroll
    for (int j = 0; j < 8; ++j) t[j] = __float2bfloat16(f[j]);
    ((uint4*)out)[i] = *(uint4*)t;
}

// ---------------------------------------------------------------------------
// Tiled transpose + fp32->bf16 convert: out[n][k] = bf16(in[k][n]).
// ---------------------------------------------------------------------------
__global__ void transpose_f32_to_bf16(const float* __restrict__ in,
                                      bf16* __restrict__ out, int K, int N) {
    __shared__ float t[32][33];
    const int n0 = blockIdx.x * 32, k0 = blockIdx.y * 32;
    const int c  = threadIdx.x & 31;
    const int rr = threadIdx.x >> 5;
#pragma unroll
    for (int i = 0; i < 4; ++i)
        t[c][rr + 8*i] = in[(size_t)(k0 + rr + 8*i) * N + n0 + c];
    __syncthreads();
#pragma unroll
    for (int i = 0; i < 4; ++i)
        out[(size_t)(n0 + rr + 8*i) * K + k0 + c] = __float2bfloat16(t[rr + 8*i][c]);
}

// ---------------------------------------------------------------------------
// GEMM v3: C[M,N] = A(bf16)[M,K] @ Bt(bf16)[N,K]. 128x128 tile, BK=64
// (half the barrier drains of BK=32; 32 KB LDS keeps ~5 blocks/CU).
// global_load_lds width=16 into unpadded [128][64] with XOR swizzle:
// LDS granule p of row r holds global granule p^(r&7); DMA lanes pre-permute
// the GLOBAL fetch (wave-uniform LDS dest preserved); frag reads at granule
// (kp*4+quad)^(l16&7) -> 2-way conflicts (free). Verified r7: conflicts = 0.
// ---------------------------------------------------------------------------
template<int EPI>
__global__ __launch_bounds__(256, 2)
void gemm_lds(const bf16* __restrict__ A, const bf16* __restrict__ Bt,
              float* __restrict__ Cmat, int N, int K,
              bf16* __restrict__ qb, bf16* __restrict__ kb, bf16* __restrict__ vb)
{
    __shared__ bf16 Alds[128][64];   // 16 KB
    __shared__ bf16 Blds[128][64];   // 16 KB

    const int tid  = threadIdx.x;
    const int wave = tid >> 6, lane = tid & 63;
    const int quad = lane >> 4, l16 = lane & 15;
    const int wm   = (wave >> 1) * 64, wn = (wave & 1) * 64;
    const size_t row0 = (size_t)blockIdx.y * 128;
    const size_t col0 = (size_t)blockIdx.x * 128;

    const f32x4 z4 = {0.f, 0.f, 0.f, 0.f};
    f32x4 acc[4][4];
#pragma unroll
    for (int mi = 0; mi < 4; ++mi)
#pragma unroll
        for (int ni = 0; ni < 4; ++ni) acc[mi][ni] = z4;

    // DMA staging: wave w, instr j covers rows w*32+j*8 .. +7.
    // lane l -> row +(l>>3), global granule (l&7)^((l>>3)&7)  [swizzle]
    const int grow = lane >> 3;                       // 0..7
    const int gcol = ((lane & 7) ^ (lane >> 3)) * 8;  // swizzled granule
    const bf16* pA = A  + (row0 + wave*32 + grow) * (size_t)K + gcol;
    const bf16* pB = Bt + (col0 + wave*32 + grow) * (size_t)K + gcol;
    bf16* lA = &Alds[wave*32][0];
    bf16* lB = &Blds[wave*32][0];

    // frag-read swizzle base (elements): granule (kp*4+quad)^(l16&7)
    const int fsw = (l16 & 7);

    for (int k0 = 0; k0 < K; k0 += 64) {
#pragma unroll
        for (int j = 0; j < 4; ++j)
            async16(lA + j*512, pA + (size_t)j*8*K + k0);
#pragma unroll
        for (int j = 0; j < 4; ++j)
            async16(lB + j*512, pB + (size_t)j*8*K + k0);
        __syncthreads();   // drains vmcnt (DMA complete) + barrier

#pragma unroll
        for (int kp = 0; kp < 2; ++kp) {
            const int fg = ((kp*4 + quad) ^ fsw) * 8;
            bf16x8v af[4], bfr[4];
#pragma unroll
            for (int i = 0; i < 4; ++i) {
                af[i]  = *(const bf16x8v*)(&Alds[wm + i*16 + l16][fg]);
                bfr[i] = *(const bf16x8v*)(&Blds[wn + i*16 + l16][fg]);
            }
#pragma unroll
            for (int mi = 0; mi < 4; ++mi)
#pragma unroll
                for (int ni = 0; ni < 4; ++ni)
                    acc[mi][ni] = mfma16(af[mi], bfr[ni], acc[mi][ni]);
        }
        __syncthreads();   // protect LDS before next DMA
    }

#pragma unroll
    for (int mi = 0; mi < 4; ++mi) {
        const size_t rowb = row0 + wm + mi*16 + quad*4;
#pragma unroll
        for (int ni = 0; ni < 4; ++ni) {
            const size_t col = col0 + wn + ni*16 + l16;
#pragma unroll
            for (int r = 0; r < 4; ++r) {
                const float v = acc[mi][ni][r];
                if constexpr (EPI == 0) {
                    Cmat[(rowb + r) * N + col] = v;
                } else {
                    const int rowi = (int)(rowb + r);
                    const int b  = rowi >> 11;
                    const int t  = rowi & (T_ - 1);
                    const int coli = (int)col;
                    const int type = coli >> 10;
                    const int cc2  = coli & (C_ - 1);
                    const int h = cc2 >> 6, d = cc2 & (HD_ - 1);
                    const int bh = b * H_ + h;
                    if (type == 0)
                        qb[((size_t)bh * T_ + t) * HD_ + d] = __float2bfloat16(v * QSCALE);
                    else if (type == 1)
                        kb[((size_t)bh * T_ + t) * HD_ + d] = __float2bfloat16(v);
                    else
                        vb[((size_t)bh * HD_ + d) * T_ + t] = __float2bfloat16(v);
                }
            }
        }
    }
}

// ---------------------------------------------------------------------------
// Flash attention v6 (causal): paired q-tiles {bx,15-bx} (uniform 34 iters),
// double-buffered K/V LDS (one barrier/chunk), register prefetch, static-max
// log2-domain softmax, and the PERMUTED-KEY S^T trick:
//   S^T = mfma(A=K-frag, B=Q-frag) with K rows loaded in permuted order
//   key(mk,mloc) = (mk>>1)*32 + (mloc>>2)*8 + (mk&1)*4 + (mloc&3)
// so the S^T C-fragment is IN-LANE identical to the PV A-fragment layout
// (V-side permutation is identity). P-frags = in-lane exp2+pack; NO P LDS
// round-trip, no cross-lane ops in the chunk loop. l via per-lane partials,
// reduced once per tile (2 shfl_xor + tiny LDS redistribute).
// ---------------------------------------------------------------------------
#define KP 72   // 64+8
#define VP 72

__global__ __launch_bounds__(256, 3)
void attn_pair(const bf16* __restrict__ qb, const bf16* __restrict__ kb,
               const bf16* __restrict__ vb, bf16* __restrict__ attn)
{
    __shared__ bf16 Klds[2][64][KP];     // 18.4 KB  K[key][d]
    __shared__ bf16 Vlds[2][64][VP];     // 18.4 KB  V[d][key]
    __shared__ float Llds[4][2][16];     // 0.5 KB   per-wave l redistribute

    const int tid  = threadIdx.x;
    const int wave = tid >> 6, lane = tid & 63;
    const int quad = lane >> 4, l16 = lane & 15;
    const int bh   = blockIdx.y;

    const bf16* Q  = qb + (size_t)bh * T_ * HD_;
    const bf16* Kp = kb + (size_t)bh * T_ * HD_;
    const bf16* Vp = vb + (size_t)bh * HD_ * T_;

    const int kr = tid >> 3;          // 0..31
    const int kc = (tid & 7) * 8;     // 0..56

    const int b = bh >> 4, h = bh & (H_ - 1);
    const f32x4 z4 = {0.f, 0.f, 0.f, 0.f};

    // permuted K-row base for A-operand loads: row(mk,l16) = base + (mk>>1)*32 + (mk&1)*4
    const int krow_base = ((l16 >> 2) * 8) + (l16 & 3);

    const int tiles[2] = { (int)blockIdx.x, 15 - (int)blockIdx.x };

    // preload chunk 0 (keys 0..63) — shared key-space across both tiles
    uint4 kreg0 = *(const uint4*)(Kp + (size_t)kr        * HD_ + kc);
    uint4 kreg1 = *(const uint4*)(Kp + (size_t)(kr + 32) * HD_ + kc);
    uint4 vreg0 = *(const uint4*)(Vp + (size_t)kr        * T_  + kc);
    uint4 vreg1 = *(const uint4*)(Vp + (size_t)(kr + 32) * T_  + kc);

    int p = 0;   // LDS buffer parity (runs continuously across both tiles)

#pragma unroll 1
    for (int tt = 0; tt < 2; ++tt) {
        const int q0b = tiles[tt] * 128;
        const int q0w = q0b + wave * 32;

        // Q frags [nq][kp]: B-operand layout n=l16 (qrow), k=quad*8+j (d)
        bf16x8v qf[2][2];
#pragma unroll
        for (int nq = 0; nq < 2; ++nq)
#pragma unroll
            for (int kp = 0; kp < 2; ++kp)
                qf[nq][kp] = *(const bf16x8v*)(Q + (size_t)(q0w + nq*16 + l16) * HD_ + kp*32 + quad*8);

        f32x4 o[2][4];
#pragma unroll
        for (int nq = 0; nq < 2; ++nq)
#pragma unroll
            for (int di = 0; di < 4; ++di) o[nq][di] = z4;
        float l_nq[2] = {0.f, 0.f};

        const int kend = q0b + 128;

#pragma unroll 1
        for (int k0 = 0; k0 < kend; k0 += 64) {
            // stage prefetched regs into buffer p
            *(uint4*)(&Klds[p][kr][kc])      = kreg0;
            *(uint4*)(&Klds[p][kr + 32][kc]) = kreg1;
            *(uint4*)(&Vlds[p][kr][kc])      = vreg0;
            *(uint4*)(&Vlds[p][kr + 32][kc]) = vreg1;
            __syncthreads();   // single barrier per chunk

            // prefetch next chunk (or next tile's chunk 0)
            const int kn = (k0 + 64 < kend) ? (k0 + 64) : 0;
            kreg0 = *(const uint4*)(Kp + (size_t)(kn + kr)      * HD_ + kc);
            kreg1 = *(const uint4*)(Kp + (size_t)(kn + kr + 32) * HD_ + kc);
            vreg0 = *(const uint4*)(Vp + (size_t)kr        * T_ + kn + kc);
            vreg1 = *(const uint4*)(Vp + (size_t)(kr + 32) * T_ + kn + kc);

            if (k0 <= q0w + 31) {   // wave-uniform causal skip
                // ---- S^T = K·Q^T : 4 key-tiles (permuted) x 2 qrow-tiles ----
                f32x4 st[4][2];
#pragma unroll
                for (int mk = 0; mk < 4; ++mk)
#pragma unroll
                    for (int nq = 0; nq < 2; ++nq) st[mk][nq] = z4;
#pragma unroll
                for (int kp = 0; kp < 2; ++kp) {
                    bf16x8v kf[4];
#pragma unroll
                    for (int mk = 0; mk < 4; ++mk)
                        kf[mk] = *(const bf16x8v*)(&Klds[p][krow_base + (mk>>1)*32 + (mk&1)*4][kp*32 + quad*8]);
#pragma unroll
                    for (int mk = 0; mk < 4; ++mk) {
                        st[mk][0] = mfma16(kf[mk], qf[0][kp], st[mk][0]);
                        st[mk][1] = mfma16(kf[mk], qf[1][kp], st[mk][1]);
                    }
                }
                // ---- causal mask (chunks straddling the diagonal only) ----
                if (k0 + 63 > q0w) {
#pragma unroll
                    for (int mk = 0; mk < 4; ++mk) {
                        const int keyb = k0 + (mk>>1)*32 + quad*8 + (mk&1)*4;
#pragma unroll
                        for (int nq = 0; nq < 2; ++nq) {
                            const int qrow = q0w + nq*16 + l16;
#pragma unroll
                            for (int r = 0; r < 4; ++r)
                                if (keyb + r > qrow) st[mk][nq][r] = -3.0e38f;
                        }
                    }
                }
                // ---- exp2 + l partials + IN-LANE pack to PV A-frags ----
                bf16x8v pa[2][2];
#pragma unroll
                for (int nq = 0; nq < 2; ++nq) {
#pragma unroll
                    for (int kp = 0; kp < 2; ++kp) {
                        union { bf16x8v v; bf16 hh[8]; } u;
                        float sum = 0.f;
#pragma unroll
                        for (int jh = 0; jh < 2; ++jh) {
                            const int mk = kp*2 + jh;
#pragma unroll
                            for (int r = 0; r < 4; ++r) {
                                const float e = exp2_hw(st[mk][nq][r]);
                                sum += e;
                                u.hh[jh*4 + r] = __float2bfloat16(e);
                            }
                        }
                        l_nq[nq] += sum;
                        pa[nq][kp] = u.v;
                    }
                }
                // ---- O += P V  (V-side key permutation is identity) ----
#pragma unroll
                for (int kp = 0; kp < 2; ++kp)
#pragma unroll
                    for (int di = 0; di < 4; ++di) {
                        const bf16x8v vf = *(const bf16x8v*)(&Vlds[p][di*16 + l16][kp*32 + quad*8]);
                        o[0][di] = mfma16(pa[0][kp], vf, o[0][di]);
                        o[1][di] = mfma16(pa[1][kp], vf, o[1][di]);
                    }
            }
            p ^= 1;
        }

        // ---- epilogue: reduce l across quads, redistribute, normalize ----
#pragma unroll
        for (int nq = 0; nq < 2; ++nq) {
            float l = l_nq[nq];
            l += __shfl_xor(l, 16);
            l += __shfl_xor(l, 32);
            if (quad == 0) Llds[wave][nq][l16] = l;
        }
        // wave-internal DS ordering: read sees the write
#pragma unroll
        for (int nq = 0; nq < 2; ++nq) {
            const f32x4 lv = *(const f32x4*)(&Llds[wave][nq][quad*4]);
#pragma unroll
            for (int r = 0; r < 4; ++r) {
                const float inv = 1.0f / lv[r];
                const int t = q0w + nq*16 + quad*4 + r;
                const size_t base = ((size_t)(b * T_ + t)) * C_ + h * HD_;
#pragma unroll
                for (int di = 0; di < 4; ++di)
                    attn[base + di*16 + l16] = __float2bfloat16(o[nq][di][r] * inv);
            }
        }
    }
}

// ---------------------------------------------------------------------------
// Workspace layout (MiB from d_ws), total 72 MiB:
//   [ 0,16)  q    bf16 [64][2048][64]  (pre-scaled 0.125*log2e)
//   [16,32)  k    bf16 [64][2048][64]
//   [32,48)  v    bf16 [64][64][2048]  (transposed [bh][d][t])
//   [48,64)  xb   bf16 [8192][1024]  -- aliased -> attnb (xb dead after GEMM1)
//   [64,70)  wt_qkv bf16 [3072][1024]
//   [70,72)  wt_out bf16 [1024][1024]
// ---------------------------------------------------------------------------
extern "C" void kernel_launch(void* const* d_in, const int* in_sizes, int n_in,
                              void* d_out, int out_size, void* d_ws, size_t ws_size,
                              hipStream_t stream)
{
    const float* x     = (const float*)d_in[0];
    const float* w_qkv = (const float*)d_in[1];
    const float* w_out = (const float*)d_in[2];
    float* out = (float*)d_out;

    char* ws = (char*)d_ws;
    bf16* qb     = (bf16*)(ws);
    bf16* kb     = (bf16*)(ws + (size_t)16 * 1024 * 1024);
    bf16* vb     = (bf16*)(ws + (size_t)32 * 1024 * 1024);
    bf16* xb     = (bf16*)(ws + (size_t)48 * 1024 * 1024);
    bf16* attnb  = xb;   // alias: xb consumed by GEMM1 before attn writes
    bf16* wtqkv  = (bf16*)(ws + (size_t)64 * 1024 * 1024);
    bf16* wtout  = (bf16*)(ws + (size_t)70 * 1024 * 1024);

    // 0) x -> bf16 (enables global_load_lds staging in GEMM1)
    convert_f32_bf16<<<dim3((M_*C_)/(8*256)), 256, 0, stream>>>(x, xb);

    // 1) weights -> bf16 transposed [N][K]
    transpose_f32_to_bf16<<<dim3(N1_/32, C_/32), 256, 0, stream>>>(w_qkv, wtqkv, C_, N1_);
    transpose_f32_to_bf16<<<dim3(C_/32,  C_/32), 256, 0, stream>>>(w_out, wtout, C_, C_);

    // 2) qkv = xb @ w_qkv, scatter q/k/v
    gemm_lds<1><<<dim3(N1_/128, M_/128), 256, 0, stream>>>(
        xb, wtqkv, nullptr, N1_, C_, qb, kb, vb);

    // 3) causal flash attention, paired-tile balanced, permuted-key S^T
    attn_pair<<<dim3(8, BH_), 256, 0, stream>>>(qb, kb, vb, attnb);

    // 4) out = attn @ w_out (fp32)
    gemm_lds<0><<<dim3(C_/128, M_/128), 256, 0, stream>>>(
        attnb, wtout, out, C_, C_, nullptr, nullptr, nullptr);
}